// Round 6
// baseline (131.918 us; speedup 1.0000x reference)
//
#include <hip/hip_runtime.h>

#define NN 128
#define CC_ 16
#define HH 32
#define WW 32
#define DD 4096   // 16*16*16 pooled features per sample
#define ND (NN*DD)

typedef float v2f __attribute__((ext_vector_type(2)));

// c = sqrt(0.5*log2(e)); folded into the means so the per-term exponent is
// exp2(-(q*q)) with the negate absorbed by the v_exp input modifier.
#define MU_SCALE 0.8493218002880191f

// Scheduling fence: VALU may NOT cross; SALU(0x4)+VMEM(0x10)+VMEM_READ(0x20)
// +DS(0x80) may cross (keeps next-j loads pipelined across phases).
#define SBAR() __builtin_amdgcn_sched_barrier(0xB4)

// ---------------------------------------------------------------------------
// Kernel 1: fused 2x2 avg-pool. FLOAT4-interleaved output:
//   wmv[n*DD+d] = {MU_SCALE*ma, MU_SCALE*mb, va, vb}
// Thread 0 zeroes d_out (poisoned 0xAA before every launch).
// ---------------------------------------------------------------------------
__global__ __launch_bounds__(256) void pool_kernel(
    const float* __restrict__ mu_a, const float* __restrict__ lv_a,
    const float* __restrict__ mu_b, const float* __restrict__ lv_b,
    float4* __restrict__ wmv, float* __restrict__ out)
{
    int t = blockIdx.x * 256 + threadIdx.x;
    if (t == 0) out[0] = 0.0f;

    int wo = t & 15;
    int ho = (t >> 4) & 15;
    int c  = (t >> 8) & 15;
    int n  = t >> 12;

    int base = ((n * CC_ + c) * HH + 2 * ho) * WW + 2 * wo;

    float2 a0 = *(const float2*)(mu_a + base);
    float2 a1 = *(const float2*)(mu_a + base + WW);
    float2 la0 = *(const float2*)(lv_a + base);
    float2 la1 = *(const float2*)(lv_a + base + WW);
    float2 b0 = *(const float2*)(mu_b + base);
    float2 b1 = *(const float2*)(mu_b + base + WW);
    float2 lb0 = *(const float2*)(lv_b + base);
    float2 lb1 = *(const float2*)(lv_b + base + WW);

    const float ms = 0.25f * MU_SCALE;
    float ma_v = ms * (a0.x + a0.y + a1.x + a1.y);
    float mb_v = ms * (b0.x + b0.y + b1.x + b1.y);
    float va_v = 0.0625f * (__expf(la0.x) + __expf(la0.y) + __expf(la1.x) + __expf(la1.y));
    float vb_v = 0.0625f * (__expf(lb0.x) + __expf(lb0.y) + __expf(lb1.x) + __expf(lb1.y));

    wmv[t] = make_float4(ma_v, mb_v, va_v, vb_v);
}

// ---------------------------------------------------------------------------
// Kernel 2: triangle-symmetric pair sums.
// R23 model (survived R18-R22): TRANS-THROUGHPUT bound. Five structurally
// different schedules all measured 103-104 cy/group == 4 trans x ~26 cy;
// occupancy (45%->30%), load volume (2x), and forced ILP each moved nothing.
// gfx950 trans unit accepts ~1 wave64 op / 25 cy (issue 8 cy, hence
// VALUBusy ~52% via the gfx94x formula). Fix = cut trans demand: NR-rsqrt
// on the VALU (R18's idea) + R22's proven sched_barrier fences for chain
// parallelism (R18 failed only because VGPR 28 serialized the chains).
// Demand: trans 2x25=50 cy/group, VALU ~38 cy/group -> balanced, overlapped
// across waves. Hardware exp2 kept (poly-exp2 would unbalance: 58>50).
// Diagnostic: VGPR must land 90-130; pair predicted 24-32 us.
// ---------------------------------------------------------------------------
__device__ __forceinline__ void pair_group(
    v2f& acc, v2f mi, v2f mj, v2f vi, v2f vj)
{
    v2f dd = mi - mj;          // v_pk_add
    v2f s  = vi + vj;          // v_pk_add
    v2f r;
    r.x = __builtin_amdgcn_rsqf(s.x);
    r.y = __builtin_amdgcn_rsqf(s.y);
    v2f q  = dd * r;           // v_pk_mul
    v2f qq = q * q;            // v_pk_mul
    v2f e;
    e.x = __builtin_amdgcn_exp2f(-qq.x);
    e.y = __builtin_amdgcn_exp2f(-qq.y);
    acc += e * r;              // v_pk_fma
}

__device__ __forceinline__ void pair_group_w(
    v2f& acc, v2f w, v2f mi, v2f mj, v2f vi, v2f vj)
{
    v2f dd = mi - mj;
    v2f s  = vi + vj;
    v2f r;
    r.x = __builtin_amdgcn_rsqf(s.x);
    r.y = __builtin_amdgcn_rsqf(s.y);
    v2f q  = dd * r;
    v2f qq = q * q;
    v2f e;
    e.x = __builtin_amdgcn_exp2f(-qq.x);
    e.y = __builtin_amdgcn_exp2f(-qq.y);
    v2f er = e * r;
    acc += w * er;
}

// NR seed: classic bit hack (VALU int ops, 2 per element).
__device__ __forceinline__ v2f rsq_seed(v2f s)
{
    v2f y;
    y.x = __int_as_float(0x5f375a86 - (__float_as_int(s.x) >> 1));
    y.y = __int_as_float(0x5f375a86 - (__float_as_int(s.y) >> 1));
    return y;
}

// One NR step: y *= (1.5 + h*y*y), h = -0.5*s. 3 pk ops.
#define NR_STEP(y, h) do { v2f _t = (y) * (y); v2f _u = (h) * _t + (v2f){1.5f, 1.5f}; (y) = (y) * _u; } while (0)

// One fenced batch of 6 v2f-groups for i-rows (p0,p1): 12 NR-rsqrt chains
// on the VALU (phase-fenced for ILP), 12 hardware exp2 (the only trans).
__device__ __forceinline__ void batch6(
    v2f& aa, v2f& bb, v2f& ab,
    v2f ma0, v2f ma1, v2f mb0, v2f mb1,
    v2f va0, v2f va1, v2f vb0, v2f vb1,
    v2f jma2, v2f jmb2, v2f jva2, v2f jvb2)
{
    const v2f mhalf = (v2f){-0.5f, -0.5f};
    v2f s0 = va0 + jva2, d0 = ma0 - jma2;   // aa p0
    v2f s1 = va1 + jva2, d1 = ma1 - jma2;   // aa p1
    v2f s2 = vb0 + jvb2, d2 = mb0 - jmb2;   // bb p0
    v2f s3 = vb1 + jvb2, d3 = mb1 - jmb2;   // bb p1
    v2f s4 = va0 + jvb2, d4 = ma0 - jmb2;   // ab p0
    v2f s5 = va1 + jvb2, d5 = ma1 - jmb2;   // ab p1
    v2f y0 = rsq_seed(s0), y1 = rsq_seed(s1), y2 = rsq_seed(s2);
    v2f y3 = rsq_seed(s3), y4 = rsq_seed(s4), y5 = rsq_seed(s5);
    v2f h0 = mhalf * s0, h1 = mhalf * s1, h2 = mhalf * s2;
    v2f h3 = mhalf * s3, h4 = mhalf * s4, h5 = mhalf * s5;
    SBAR();
    // 3 NR iterations, phase-fenced so all 6 chains stay interleaved.
    NR_STEP(y0, h0); NR_STEP(y1, h1); NR_STEP(y2, h2);
    NR_STEP(y3, h3); NR_STEP(y4, h4); NR_STEP(y5, h5);
    SBAR();
    NR_STEP(y0, h0); NR_STEP(y1, h1); NR_STEP(y2, h2);
    NR_STEP(y3, h3); NR_STEP(y4, h4); NR_STEP(y5, h5);
    SBAR();
    NR_STEP(y0, h0); NR_STEP(y1, h1); NR_STEP(y2, h2);
    NR_STEP(y3, h3); NR_STEP(y4, h4); NR_STEP(y5, h5);
    SBAR();
    v2f q;
    v2f t0, t1, t2, t3, t4, t5;
    q = d0 * y0; t0 = q * q;
    q = d1 * y1; t1 = q * q;
    q = d2 * y2; t2 = q * q;
    q = d3 * y3; t3 = q * q;
    q = d4 * y4; t4 = q * q;
    q = d5 * y5; t5 = q * q;
    SBAR();
    v2f e0, e1, e2, e3, e4, e5;
    e0.x = __builtin_amdgcn_exp2f(-t0.x); e0.y = __builtin_amdgcn_exp2f(-t0.y);
    e1.x = __builtin_amdgcn_exp2f(-t1.x); e1.y = __builtin_amdgcn_exp2f(-t1.y);
    e2.x = __builtin_amdgcn_exp2f(-t2.x); e2.y = __builtin_amdgcn_exp2f(-t2.y);
    e3.x = __builtin_amdgcn_exp2f(-t3.x); e3.y = __builtin_amdgcn_exp2f(-t3.y);
    e4.x = __builtin_amdgcn_exp2f(-t4.x); e4.y = __builtin_amdgcn_exp2f(-t4.y);
    e5.x = __builtin_amdgcn_exp2f(-t5.x); e5.y = __builtin_amdgcn_exp2f(-t5.y);
    SBAR();
    aa += e0 * y0;  aa += e1 * y1;
    bb += e2 * y2;  bb += e3 * y3;
    ab += e4 * y4;  ab += e5 * y5;
    // no trailing fence: let next batch's VALU overlap the exp drain
}

// One fenced batch of 4 ab-only v2f-groups, same structure.
__device__ __forceinline__ void batch4_ab(
    v2f& ab,
    v2f ma0, v2f ma1, v2f ma2, v2f ma3,
    v2f va0, v2f va1, v2f va2, v2f va3,
    v2f jmb2, v2f jvb2)
{
    const v2f mhalf = (v2f){-0.5f, -0.5f};
    v2f s0 = va0 + jvb2, d0 = ma0 - jmb2;
    v2f s1 = va1 + jvb2, d1 = ma1 - jmb2;
    v2f s2 = va2 + jvb2, d2 = ma2 - jmb2;
    v2f s3 = va3 + jvb2, d3 = ma3 - jmb2;
    v2f y0 = rsq_seed(s0), y1 = rsq_seed(s1);
    v2f y2 = rsq_seed(s2), y3 = rsq_seed(s3);
    v2f h0 = mhalf * s0, h1 = mhalf * s1;
    v2f h2 = mhalf * s2, h3 = mhalf * s3;
    SBAR();
    NR_STEP(y0, h0); NR_STEP(y1, h1); NR_STEP(y2, h2); NR_STEP(y3, h3);
    SBAR();
    NR_STEP(y0, h0); NR_STEP(y1, h1); NR_STEP(y2, h2); NR_STEP(y3, h3);
    SBAR();
    NR_STEP(y0, h0); NR_STEP(y1, h1); NR_STEP(y2, h2); NR_STEP(y3, h3);
    SBAR();
    v2f q;
    v2f t0, t1, t2, t3;
    q = d0 * y0; t0 = q * q;
    q = d1 * y1; t1 = q * q;
    q = d2 * y2; t2 = q * q;
    q = d3 * y3; t3 = q * q;
    SBAR();
    v2f e0, e1, e2, e3;
    e0.x = __builtin_amdgcn_exp2f(-t0.x); e0.y = __builtin_amdgcn_exp2f(-t0.y);
    e1.x = __builtin_amdgcn_exp2f(-t1.x); e1.y = __builtin_amdgcn_exp2f(-t1.y);
    e2.x = __builtin_amdgcn_exp2f(-t2.x); e2.y = __builtin_amdgcn_exp2f(-t2.y);
    e3.x = __builtin_amdgcn_exp2f(-t3.x); e3.y = __builtin_amdgcn_exp2f(-t3.y);
    SBAR();
    ab += e0 * y0;  ab += e1 * y1;  ab += e2 * y2;  ab += e3 * y3;
}

// Process j in [jlo, jhi) against rows i0..i0+7 (3-range triangle split).
__device__ __forceinline__ void run_range8(
    int jlo, int jhi, int i0, int d,
    const float4* __restrict__ wmv,
    v2f& acc_aa, v2f& acc_bb, v2f& acc_ab,
    const v2f pma[4], const v2f pmb[4], const v2f pva[4], const v2f pvb[4])
{
    const int below_end = min(jhi, i0);
    const int band_lo   = max(jlo, i0);
    const int band_hi   = min(jhi, i0 + 8);
    const int above_lo  = max(jlo, i0 + 8);

    // --- below diagonal: full aa + bb + ab (12 groups per 16B load),
    //     two fenced 6-group batches per j ---
#pragma unroll 2
    for (int j = jlo; j < below_end; ++j) {
        float4 jr = wmv[j * DD + d];           // one dwordx4
        v2f jma2 = (v2f){jr.x, jr.x};
        v2f jmb2 = (v2f){jr.y, jr.y};
        v2f jva2 = (v2f){jr.z, jr.z};
        v2f jvb2 = (v2f){jr.w, jr.w};
        batch6(acc_aa, acc_bb, acc_ab,
               pma[0], pma[1], pmb[0], pmb[1],
               pva[0], pva[1], pvb[0], pvb[1],
               jma2, jmb2, jva2, jvb2);
        batch6(acc_aa, acc_bb, acc_ab,
               pma[2], pma[3], pmb[2], pmb[3],
               pva[2], pva[3], pvb[2], pvb[3],
               jma2, jmb2, jva2, jvb2);
    }

    // --- diagonal band (8 iters): per-row half-weights {1, .5, 0};
    //     tiny fraction of total groups, keep the simple v_rsq path ---
    for (int j = band_lo; j < band_hi; ++j) {
        float4 jr = wmv[j * DD + d];
        v2f jma2 = (v2f){jr.x, jr.x};
        v2f jmb2 = (v2f){jr.y, jr.y};
        v2f jva2 = (v2f){jr.z, jr.z};
        v2f jvb2 = (v2f){jr.w, jr.w};
        v2f w[4];
#pragma unroll
        for (int p = 0; p < 4; ++p) {
            int r0 = i0 + 2 * p, r1 = r0 + 1;
            w[p].x = (j < r0) ? 1.0f : (j == r0 ? 0.5f : 0.0f);
            w[p].y = (j < r1) ? 1.0f : (j == r1 ? 0.5f : 0.0f);
        }
#pragma unroll
        for (int p = 0; p < 4; ++p) {
            pair_group_w(acc_aa, w[p], pma[p], jma2, pva[p], jva2);
            pair_group_w(acc_bb, w[p], pmb[p], jmb2, pvb[p], jvb2);
            pair_group(acc_ab, pma[p], jmb2, pva[p], jvb2);
        }
    }

    // --- above diagonal: ab only, one fenced 4-group batch per j ---
#pragma unroll 2
    for (int j = above_lo; j < jhi; ++j) {
        float4 jr = wmv[j * DD + d];
        v2f jmb2 = (v2f){jr.y, jr.y};
        v2f jvb2 = (v2f){jr.w, jr.w};
        batch4_ab(acc_ab,
                  pma[0], pma[1], pma[2], pma[3],
                  pva[0], pva[1], pva[2], pva[3],
                  jmb2, jvb2);
    }
}

// Load a tile's 8 rows and run one (tile, chunk) unit.
__device__ __forceinline__ void process_unit8(
    int tile, int chunk, int d, const float4* __restrict__ wmv,
    v2f& acc_aa, v2f& acc_bb, v2f& acc_ab)
{
    const int i0 = tile * 8;
    v2f pma[4], pmb[4], pva[4], pvb[4];
#pragma unroll
    for (int p = 0; p < 4; ++p) {
        float4 r0 = wmv[(i0 + 2 * p) * DD + d];
        float4 r1 = wmv[(i0 + 2 * p + 1) * DD + d];
        pma[p] = (v2f){r0.x, r1.x};
        pmb[p] = (v2f){r0.y, r1.y};
        pva[p] = (v2f){r0.z, r1.z};
        pvb[p] = (v2f){r0.w, r1.w};
    }
    run_range8(chunk * 16, chunk * 16 + 16, i0, d, wmv,
               acc_aa, acc_bb, acc_ab, pma, pmb, pva, pvb);
}

// ---------------------------------------------------------------------------
// Unit schedule (R20's proven best): 16 tiles (8 rows each) x 8 chunks
// (16 j each) = 128 units, 2048 blocks total (exact capacity -- 2x grids
// regressed +20us in R19/R21). Heavy blocks dispatch first.
// ---------------------------------------------------------------------------
__device__ __forceinline__ uint2 unit_for(int y) {
    if (y < 56) {            // below-diag full units (tiles 2u,2u+1, c<u)
        int u, kk;
        if      (y < 2)  { u = 1; kk = y; }
        else if (y < 6)  { u = 2; kk = y - 2; }
        else if (y < 12) { u = 3; kk = y - 6; }
        else if (y < 20) { u = 4; kk = y - 12; }
        else if (y < 30) { u = 5; kk = y - 20; }
        else if (y < 42) { u = 6; kk = y - 30; }
        else             { u = 7; kk = y - 42; }
        return make_uint2(2 * u + kk / u, kk % u);
    } else if (y < 64) {     // odd-tile diagonal
        int u = y - 56;
        return make_uint2(2 * u + 1, u);
    } else if (y < 72) {     // even-tile diagonal
        int u = y - 64;
        return make_uint2(2 * u, u);
    } else {                 // above-diag ab-only (tiles 2u,2u+1, c>u)
        int k = y - 72;
        int u, kk;
        if      (k < 14) { u = 0; kk = k; }
        else if (k < 26) { u = 1; kk = k - 14; }
        else if (k < 36) { u = 2; kk = k - 26; }
        else if (k < 44) { u = 3; kk = k - 36; }
        else if (k < 50) { u = 4; kk = k - 44; }
        else if (k < 54) { u = 5; kk = k - 50; }
        else             { u = 6; kk = k - 54; }
        int w = 7 - u;
        return make_uint2(2 * u + kk / w, u + 1 + kk % w);
    }
}

__global__ __launch_bounds__(256) void pair_kernel(
    const float4* __restrict__ wmv, float* __restrict__ out)
{
    const int d = blockIdx.x * 256 + threadIdx.x;

    uint2 U = unit_for(blockIdx.y);

    v2f acc_aa = (v2f){0.0f, 0.0f};
    v2f acc_bb = (v2f){0.0f, 0.0f};
    v2f acc_ab = (v2f){0.0f, 0.0f};

    process_unit8((int)U.x, (int)U.y, d, wmv, acc_aa, acc_bb, acc_ab);

    // vaa + vbb - 2 vab = 2 * (half_aa + half_bb - half_ab)
    float part = 2.0f * ((acc_aa.x + acc_aa.y) + (acc_bb.x + acc_bb.y)
                       - (acc_ab.x + acc_ab.y));

    // wave (64-lane) shuffle reduction
#pragma unroll
    for (int off = 32; off > 0; off >>= 1)
        part += __shfl_down(part, off, 64);

    __shared__ float wsum[4];
    int lane = threadIdx.x & 63;
    int wv_  = threadIdx.x >> 6;
    if (lane == 0) wsum[wv_] = part;
    __syncthreads();
    if (threadIdx.x == 0) {
        float s = wsum[0] + wsum[1] + wsum[2] + wsum[3];
        atomicAdd(out, s);
    }
}

extern "C" void kernel_launch(void* const* d_in, const int* in_sizes, int n_in,
                              void* d_out, int out_size, void* d_ws, size_t ws_size,
                              hipStream_t stream) {
    const float* mu_a = (const float*)d_in[0];
    const float* lv_a = (const float*)d_in[1];
    const float* mu_b = (const float*)d_in[2];
    const float* lv_b = (const float*)d_in[3];
    float* out  = (float*)d_out;
    float4* wmv = (float4*)d_ws;           // ND float4 = 8 MB

    pool_kernel<<<dim3(ND / 256), 256, 0, stream>>>(mu_a, lv_a, mu_b, lv_b, wmv, out);
    pair_kernel<<<dim3(DD / 256, 128), 256, 0, stream>>>(wmv, out);
}